// Round 1
// baseline (146.656 us; speedup 1.0000x reference)
//
#include <hip/hip_runtime.h>
#include <math.h>

#define W 128
#define LDSROWS 70

__global__ __launch_bounds__(256) void smoaw_kernel(const float* __restrict__ x,
                                                    float* __restrict__ out) {
    const int bid   = blockIdx.x;
    const int plane = bid >> 1;
    const int half  = bid & 1;
    const int r0    = half << 6;     // 0 or 64
    const int rbase = r0 - 3;        // first staged row (may be <0)

    __shared__ float lds[LDSROWS * W];

    const float* __restrict__ xp = x   + (size_t)plane * (128 * W);
    float* __restrict__       op = out + (size_t)plane * (128 * W);

    const int tid = threadIdx.x;

    // Stage rows rbase..rbase+69 (valid ones), coalesced float4
    for (int i = tid; i < LDSROWS * (W / 4); i += 256) {
        const int rl = i >> 5;
        const int c4 = (i & 31) << 2;
        const int rg = rbase + rl;
        if ((unsigned)rg < 128u) {
            const float4 v = *reinterpret_cast<const float4*>(xp + rg * W + c4);
            *reinterpret_cast<float4*>(&lds[rl * W + c4]) = v;
        }
    }
    __syncthreads();

    const int c   = tid & 127;       // column owned by this thread
    const int q   = tid >> 7;        // row-quarter within the half (0/1)
    const int r0q = r0 + (q << 5);   // first output row: r0q..r0q+31

    // clamped column indices (replicate-edge: neutral for min/max)
    const int co0 = (c - 3 < 0) ? 0 : c - 3;
    const int co1 = (c - 2 < 0) ? 0 : c - 2;
    const int co2 = (c - 1 < 0) ? 0 : c - 1;
    const int co4 = (c + 1 > 127) ? 127 : c + 1;
    const int co5 = (c + 2 > 127) ? 127 : c + 2;
    const int co6 = (c + 3 > 127) ? 127 : c + 3;

    // duplicate counts for the zero-padded sums (count_include_pad)
    const float cL3 = (float)((1 - c) > 0 ? (1 - c) : 0);
    const float cL5 = (float)((2 - c) > 0 ? (2 - c) : 0);
    const float cL7 = (float)((3 - c) > 0 ? (3 - c) : 0);
    const float cR3 = (float)((c - 126) > 0 ? (c - 126) : 0);
    const float cR5 = (float)((c - 125) > 0 ? (c - 125) : 0);
    const float cR7 = (float)((c - 124) > 0 ? (c - 124) : 0);

    // ring buffers (static indices after unroll -> VGPRs)
    float rn3[8], rn5[8], rn7[8];
    float rx3[8], rx5[8], rx7[8];
    float rs3[8], rs5[8], rs7[8];
    float rcx[8];

    const float INF = __builtin_inff();

#define STEP(S, J)                                                                \
    {                                                                             \
        const int rr = r0q - 3 + (S);                                             \
        float mn3, mn5, mn7, mx3, mx5, mx7, s3, s5, s7, vc;                       \
        if ((unsigned)rr < 128u) {                                                \
            const float* row = &lds[((q << 5) + (S)) * W];                        \
            const float v0 = row[co0];                                            \
            const float v1 = row[co1];                                            \
            const float v2 = row[co2];                                            \
            const float v3 = row[c];                                              \
            const float v4 = row[co4];                                            \
            const float v5 = row[co5];                                            \
            const float v6 = row[co6];                                            \
            mn3 = fminf(fminf(v2, v3), v4);                                       \
            mn5 = fminf(fminf(mn3, v1), v5);                                      \
            mn7 = fminf(fminf(mn5, v0), v6);                                      \
            mx3 = fmaxf(fmaxf(v2, v3), v4);                                       \
            mx5 = fmaxf(fmaxf(mx3, v1), v5);                                      \
            mx7 = fmaxf(fmaxf(mx5, v0), v6);                                      \
            s3 = v2 + v3 + v4;                                                    \
            s5 = s3 + v1 + v5;                                                    \
            s7 = s5 + v0 + v6;                                                    \
            s3 = s3 - cL3 * v2 - cR3 * v4;                                        \
            s5 = s5 - cL5 * v1 - cR5 * v5;                                        \
            s7 = s7 - cL7 * v0 - cR7 * v6;                                        \
            vc = v3;                                                              \
        } else {                                                                  \
            mn3 = INF;  mn5 = INF;  mn7 = INF;                                    \
            mx3 = -INF; mx5 = -INF; mx7 = -INF;                                   \
            s3 = 0.f; s5 = 0.f; s7 = 0.f; vc = 0.f;                               \
        }                                                                         \
        rn3[(J) & 7] = mn3; rn5[(J) & 7] = mn5; rn7[(J) & 7] = mn7;               \
        rx3[(J) & 7] = mx3; rx5[(J) & 7] = mx5; rx7[(J) & 7] = mx7;               \
        rs3[(J) & 7] = s3;  rs5[(J) & 7] = s5;  rs7[(J) & 7] = s7;                \
        rcx[(J) & 7] = vc;                                                        \
        if ((S) >= 6) {                                                           \
            const int a2 = ((J) + 2) & 7, a3 = ((J) + 3) & 7, a4 = ((J) + 4) & 7; \
            const int a5 = ((J) + 5) & 7, a6 = ((J) + 6) & 7, a7 = ((J) + 7) & 7; \
            const int a0 = (J) & 7;                                               \
            const float vm3 = fminf(fminf(rn3[a4], rn3[a5]), rn3[a6]);            \
            const float vm5 = fminf(fminf(fminf(fminf(rn5[a3], rn5[a4]), rn5[a5]), rn5[a6]), rn5[a7]); \
            const float vm7 = fminf(fminf(fminf(rn7[a2], rn7[a3]), fminf(rn7[a4], rn7[a5])), \
                                    fminf(fminf(rn7[a6], rn7[a7]), rn7[a0]));     \
            const float vX3 = fmaxf(fmaxf(rx3[a4], rx3[a5]), rx3[a6]);            \
            const float vX5 = fmaxf(fmaxf(fmaxf(fmaxf(rx5[a3], rx5[a4]), rx5[a5]), rx5[a6]), rx5[a7]); \
            const float vX7 = fmaxf(fmaxf(fmaxf(rx7[a2], rx7[a3]), fmaxf(rx7[a4], rx7[a5])), \
                                    fmaxf(fmaxf(rx7[a6], rx7[a7]), rx7[a0]));     \
            const float vs3 = rs3[a4] + rs3[a5] + rs3[a6];                        \
            const float vs5 = rs5[a3] + rs5[a4] + rs5[a5] + rs5[a6] + rs5[a7];    \
            const float vs7 = rs7[a2] + rs7[a3] + rs7[a4] + rs7[a5] + rs7[a6] + rs7[a7] + rs7[a0]; \
            const float av3 = vs3 * (1.f / 9.f);                                  \
            const float av5 = vs5 * (1.f / 25.f);                                 \
            const float av7 = vs7 * (1.f / 49.f);                                 \
            const int cnt = (((av3 > vm3) && (av3 < vX3)) ? 1 : 0)                \
                          + (((av5 > vm5) && (av5 < vX5)) ? 1 : 0)                \
                          + (((av7 > vm7) && (av7 < vX7)) ? 1 : 0);               \
            const float sg = (cnt == 0) ? 0.18242553f                             \
                           : (cnt == 1) ? 0.37754068f                             \
                           : (cnt == 2) ? 0.62245935f : 0.81757450f;              \
            op[(rr - 3) * W + c] = rcx[((J) + 5) & 7] * sg;                       \
        }                                                                         \
    }

    for (int blk = 0; blk < 4; ++blk) {
        #pragma unroll
        for (int j = 0; j < 8; ++j) {
            STEP(blk * 8 + j, j)
        }
    }
    #pragma unroll
    for (int j = 0; j < 6; ++j) {
        STEP(32 + j, j)
    }
#undef STEP
}

extern "C" void kernel_launch(void* const* d_in, const int* in_sizes, int n_in,
                              void* d_out, int out_size, void* d_ws, size_t ws_size,
                              hipStream_t stream) {
    const float* x = (const float*)d_in[0];
    float* out = (float*)d_out;
    const int planes = in_sizes[0] >> 14;   // elements / (128*128) = 3072
    dim3 grid(planes * 2), block(256);
    hipLaunchKernelGGL(smoaw_kernel, grid, block, 0, stream, x, out);
}

// Round 2
// 111.951 us; speedup vs baseline: 1.3100x; 1.3100x over previous
//
#include <hip/hip_runtime.h>
#include <math.h>

#define W 128
#define LDSROWS 70

__device__ __forceinline__ float min3f(float a, float b, float c) {
    return fminf(fminf(a, b), c);
}
__device__ __forceinline__ float max3f(float a, float b, float c) {
    return fmaxf(fmaxf(a, b), c);
}

__global__ __launch_bounds__(256, 4) void smoaw_kernel(const float* __restrict__ x,
                                                       float* __restrict__ out) {
    const int bid   = blockIdx.x;
    const int plane = bid >> 1;
    const int half  = bid & 1;
    const int r0    = half << 6;     // 0 or 64
    const int rbase = r0 - 3;        // first staged row (clamped)

    __shared__ float lds[LDSROWS * W];

    const float* __restrict__ xp = x   + (size_t)plane * (128 * W);
    float* __restrict__       op = out + (size_t)plane * (128 * W);

    const int tid = threadIdx.x;

    // Stage rows rbase..rbase+69 with row clamping (replicate edge rows).
    for (int i = tid; i < LDSROWS * (W / 4); i += 256) {
        const int rl = i >> 5;
        const int c4 = (i & 31) << 2;
        int rg = rbase + rl;
        rg = rg < 0 ? 0 : (rg > 127 ? 127 : rg);
        const float4 v = *reinterpret_cast<const float4*>(xp + rg * W + c4);
        *reinterpret_cast<float4*>(&lds[rl * W + c4]) = v;
    }
    __syncthreads();

    const int c   = tid & 127;       // column owned by this thread
    const int q   = tid >> 7;        // wave-uniform (0/1)
    const int r0q = r0 + (q << 5);   // first output row: r0q..r0q+31
    const int r0q_u = __builtin_amdgcn_readfirstlane(r0q);

    // clamped column indices (replicate-edge: neutral for min/max)
    const int co0 = (c - 3 < 0) ? 0 : c - 3;
    const int co1 = (c - 2 < 0) ? 0 : c - 2;
    const int co2 = (c - 1 < 0) ? 0 : c - 1;
    const int co4 = (c + 1 > 127) ? 127 : c + 1;
    const int co5 = (c + 2 > 127) ? 127 : c + 2;
    const int co6 = (c + 3 > 127) ? 127 : c + 3;

    // duplicate counts correcting sums to zero-padded semantics (columns)
    const float cL3 = (float)((1 - c) > 0 ? (1 - c) : 0);
    const float cL5 = (float)((2 - c) > 0 ? (2 - c) : 0);
    const float cL7 = (float)((3 - c) > 0 ? (3 - c) : 0);
    const float cR3 = (float)((c - 126) > 0 ? (c - 126) : 0);
    const float cR5 = (float)((c - 125) > 0 ? (c - 125) : 0);
    const float cR7 = (float)((c - 124) > 0 ? (c - 124) : 0);

    // 7 per-lane LDS base pointers; step S reads at compile-time offset S*W
    const float* prow = &lds[(q << 5) * W];
    const float* pp0 = prow + co0;
    const float* pp1 = prow + co1;
    const float* pp2 = prow + co2;
    const float* pp3 = prow + c;
    const float* pp4 = prow + co4;
    const float* pp5 = prow + co5;
    const float* pp6 = prow + co6;

    float* ob = op + (size_t)(r0q * W + c);

    // rings (all indices compile-time after unroll -> pure registers)
    float hn3[8], hn5[8], hn7[8];
    float hx3[8], hx5[8], hx7[8];
    float p3r[8], p5r[8], p7r[8];
    float cx[4];
    float P3 = 0.f, P5 = 0.f, P7 = 0.f;
    p7r[7] = 0.f;                    // P7 "before step 0"

    float sv3_0 = 0.f, sv5_0 = 0.f, sv7_0 = 0.f;    // row-0 sums (top fixup)
    float sv3_b = 0.f, sv5_b = 0.f, sv7_b = 0.f;    // row-127 sums (bottom fixup)

    const float SG0 = 0.18242553f;   // sigmoid(-1.5)
    const float SG1 = 0.37754068f;   // sigmoid(-0.5)
    const float SG2 = 0.62245935f;   // sigmoid( 0.5)
    const float SG3 = 0.81757450f;   // sigmoid( 1.5)

    #pragma unroll
    for (int S = 0; S < 38; ++S) {
        const float v0 = pp0[S * W];
        const float v1 = pp1[S * W];
        const float v2 = pp2[S * W];
        const float v3 = pp3[S * W];
        const float v4 = pp4[S * W];
        const float v5 = pp5[S * W];
        const float v6 = pp6[S * W];

        const float mn3 = min3f(v2, v3, v4);
        const float mn5 = min3f(mn3, v1, v5);
        const float mn7 = min3f(mn5, v0, v6);
        const float mx3 = max3f(v2, v3, v4);
        const float mx5 = max3f(mx3, v1, v5);
        const float mx7 = max3f(mx5, v0, v6);

        float s3 = v2 + v3 + v4;
        float s5 = s3 + v1 + v5;
        float s7 = s5 + v0 + v6;
        s3 = s3 - cL3 * v2 - cR3 * v4;
        s5 = s5 - cL5 * v1 - cR5 * v5;
        s7 = s7 - cL7 * v0 - cR7 * v6;

        P3 += s3; P5 += s5; P7 += s7;

        hn3[S & 7] = mn3; hn5[S & 7] = mn5; hn7[S & 7] = mn7;
        hx3[S & 7] = mx3; hx5[S & 7] = mx5; hx7[S & 7] = mx7;
        p3r[S & 7] = P3;  p5r[S & 7] = P5;  p7r[S & 7] = P7;
        cx[S & 3] = v3;

        if (S == 0)  { sv3_0 = s3; sv5_0 = s5; sv7_0 = s7; }
        if (S == 34) { sv3_b = s3; sv5_b = s5; sv7_b = s7; }

        if (S >= 6) {
            // vertical min/max directly from rings via min3/max3
            const float vm3 = min3f(hn3[(S - 4) & 7], hn3[(S - 3) & 7], hn3[(S - 2) & 7]);
            float vm5 = min3f(hn5[(S - 5) & 7], hn5[(S - 4) & 7], hn5[(S - 3) & 7]);
            vm5 = min3f(vm5, hn5[(S - 2) & 7], hn5[(S - 1) & 7]);
            const float vm7a = min3f(hn7[(S - 6) & 7], hn7[(S - 5) & 7], hn7[(S - 4) & 7]);
            const float vm7b = min3f(hn7[(S - 3) & 7], hn7[(S - 2) & 7], hn7[(S - 1) & 7]);
            const float vm7 = min3f(vm7a, vm7b, mn7);

            const float vX3 = max3f(hx3[(S - 4) & 7], hx3[(S - 3) & 7], hx3[(S - 2) & 7]);
            float vX5 = max3f(hx5[(S - 5) & 7], hx5[(S - 4) & 7], hx5[(S - 3) & 7]);
            vX5 = max3f(vX5, hx5[(S - 2) & 7], hx5[(S - 1) & 7]);
            const float vX7a = max3f(hx7[(S - 6) & 7], hx7[(S - 5) & 7], hx7[(S - 4) & 7]);
            const float vX7b = max3f(hx7[(S - 3) & 7], hx7[(S - 2) & 7], hx7[(S - 1) & 7]);
            const float vX7 = max3f(vX7a, vX7b, mx7);

            float vs3 = p3r[(S - 2) & 7] - p3r[(S - 5) & 7];
            float vs5 = p5r[(S - 1) & 7] - p5r[(S - 6) & 7];
            float vs7 = P7 - p7r[(S - 7) & 7];

            // row-edge fixups (wave-uniform scalar branches)
            if (S == 6 && r0q_u == 0)  { vs3 -= sv3_0; vs5 -= 2.f * sv5_0; vs7 -= 3.f * sv7_0; }
            if (S == 7 && r0q_u == 0)  { vs5 -= sv5_0; vs7 -= 2.f * sv7_0; }
            if (S == 8 && r0q_u == 0)  { vs7 -= sv7_0; }
            if (S == 35 && r0q_u == 96) { vs7 -= sv7_b; }
            if (S == 36 && r0q_u == 96) { vs5 -= sv5_b; vs7 -= 2.f * sv7_b; }
            if (S == 37 && r0q_u == 96) { vs3 -= sv3_b; vs5 -= 2.f * sv5_b; vs7 -= 3.f * sv7_b; }

            const float av3 = vs3 * (1.f / 9.f);
            const float av5 = vs5 * (1.f / 25.f);
            const float av7 = vs7 * (1.f / 49.f);

            const float w = (((av3 > vm3) && (av3 < vX3)) ? 1.f : 0.f)
                          + (((av5 > vm5) && (av5 < vX5)) ? 1.f : 0.f)
                          + (((av7 > vm7) && (av7 < vX7)) ? 1.f : 0.f);
            const float sg = (w < 0.5f) ? SG0
                           : (w < 1.5f) ? SG1
                           : (w < 2.5f) ? SG2 : SG3;

            ob[(S - 6) * W] = cx[(S - 3) & 3] * sg;
        }
    }
}

extern "C" void kernel_launch(void* const* d_in, const int* in_sizes, int n_in,
                              void* d_out, int out_size, void* d_ws, size_t ws_size,
                              hipStream_t stream) {
    const float* x = (const float*)d_in[0];
    float* out = (float*)d_out;
    const int planes = in_sizes[0] >> 14;   // 3072 planes of 128x128
    dim3 grid(planes * 2), block(256);
    hipLaunchKernelGGL(smoaw_kernel, grid, block, 0, stream, x, out);
}